// Round 4
// baseline (710.249 us; speedup 1.0000x reference)
//
#include <hip/hip_runtime.h>
#include <hip/hip_bf16.h>
#include <math.h>

typedef __bf16 bf16;
typedef __bf16 v8bf __attribute__((ext_vector_type(8)));
typedef __bf16 v4bf __attribute__((ext_vector_type(4)));
typedef float  v4f  __attribute__((ext_vector_type(4)));

#define FDIM 256

// ---------------- small utility kernels ----------------

__global__ __launch_bounds__(256) void zero_kernel(int* __restrict__ p, int n) {
  int i = blockIdx.x * 256 + threadIdx.x;
  if (i < n) p[i] = 0;
}

// distinctive flag value if workspace is too small
__global__ __launch_bounds__(256) void flag_kernel(float* __restrict__ out, int n) {
  int i = blockIdx.x * 256 + threadIdx.x;
  if (i < n) out[i] = 1.0e9f;
}

// Wt[n*256 + k] = bf16(W[k*256 + n])  (B-fragment friendly: contiguous along k)
__global__ __launch_bounds__(256) void transpose_w(const float* __restrict__ W,
                                                   bf16* __restrict__ Wt) {
  int k = blockIdx.x;   // 0..255
  int n = threadIdx.x;  // 0..255
  Wt[n * FDIM + k] = (bf16)W[k * FDIM + n];
}

__global__ __launch_bounds__(256) void hist_kernel(const int* __restrict__ dst,
                                                   int* __restrict__ counts, int E, int N) {
  for (int e = blockIdx.x * 256 + threadIdx.x; e < E; e += gridDim.x * 256) {
    int d = dst[e];
    d = d < 0 ? 0 : (d >= N ? N - 1 : d);
    atomicAdd(&counts[d], 1);
  }
}

// single-block chunked exclusive scan: counts[n] -> offsets[n+1], cursor[n]
__global__ __launch_bounds__(256) void scan_simple(const int* __restrict__ counts,
                                                   int* __restrict__ offsets,
                                                   int* __restrict__ cursor, int n) {
  __shared__ int s[257];
  int t = threadIdx.x;
  int C = (n + 255) / 256;
  int lo = t * C;
  int hi = lo + C; if (hi > n) hi = n;
  int sum = 0;
  for (int i = lo; i < hi; ++i) sum += counts[i];
  s[t] = sum;
  __syncthreads();
  if (t == 0) {
    int run = 0;
    for (int i = 0; i < 256; ++i) { int v = s[i]; s[i] = run; run += v; }
    s[256] = run;
  }
  __syncthreads();
  int run = s[t];
  for (int i = lo; i < hi; ++i) {
    offsets[i] = run;
    cursor[i] = run;
    run += counts[i];
  }
  if (t == 0) offsets[n] = s[256];
}

__global__ __launch_bounds__(256) void scatter_kernel(const int* __restrict__ src,
                                                      const int* __restrict__ dst,
                                                      const float* __restrict__ ew,
                                                      int* __restrict__ cursor,
                                                      int* __restrict__ perm_src,
                                                      float* __restrict__ perm_w,
                                                      int E, int N) {
  for (int e = blockIdx.x * 256 + threadIdx.x; e < E; e += gridDim.x * 256) {
    int d = dst[e];
    d = d < 0 ? 0 : (d >= N ? N - 1 : d);
    int pos = atomicAdd(&cursor[d], 1);
    if (pos >= 0 && pos < E) {
      int sv = src[e];
      sv = sv < 0 ? 0 : (sv >= N ? N - 1 : sv);
      perm_src[pos] = sv;
      perm_w[pos] = ew[e];
    }
  }
}

// ---------------- A-fragment loaders (8 contiguous k-elements) ----------------
__device__ inline v8bf load8(const bf16* __restrict__ p) {
  return *reinterpret_cast<const v8bf*>(p);
}
__device__ inline v8bf load8(const float* __restrict__ p) {
  float4 a = *reinterpret_cast<const float4*>(p);
  float4 b = *reinterpret_cast<const float4*>(p + 4);
  v8bf r;
  r[0] = (bf16)a.x; r[1] = (bf16)a.y; r[2] = (bf16)a.z; r[3] = (bf16)a.w;
  r[4] = (bf16)b.x; r[5] = (bf16)b.y; r[6] = (bf16)b.z; r[7] = (bf16)b.w;
  return r;
}

// ---------------- GEMM: C[M,256] = A[M,256] @ W[256,256] ----------------
// A row-major (fp32 or bf16); Bt is W pre-transposed bf16: Bt[n*256+k] = W[k][n].
// Block = 256 threads = 4 waves; block tile = 16 rows x 256 cols;
// wave w covers cols [64w, 64w+64) via 4 accumulators of 16x16.
template <typename AT>
__global__ __launch_bounds__(256) void gemm_kernel(const AT* __restrict__ A,
                                                   const bf16* __restrict__ Bt,
                                                   bf16* __restrict__ C, int M) {
  const int K = FDIM, N = FDIM;
  int row0 = blockIdx.x * 16;
  int tid = threadIdx.x;
  int wave = tid >> 6;
  int lane = tid & 63;
  int l15 = lane & 15, quad = lane >> 4;

  int ar = row0 + l15;
  if (ar >= M) ar = M - 1;

  const AT* Arow = A + (size_t)ar * K + quad * 8;
  const bf16* Bbase = Bt + (size_t)(wave * 64 + l15) * K + quad * 8;

  v4f acc[4];
#pragma unroll
  for (int nn = 0; nn < 4; ++nn) acc[nn] = (v4f){0.f, 0.f, 0.f, 0.f};

#pragma unroll
  for (int kk = 0; kk < K; kk += 32) {
    v8bf a = load8(Arow + kk);
#pragma unroll
    for (int nn = 0; nn < 4; ++nn) {
      v8bf b = *reinterpret_cast<const v8bf*>(Bbase + (size_t)nn * 16 * K + kk);
      acc[nn] = __builtin_amdgcn_mfma_f32_16x16x32_bf16(a, b, acc[nn], 0, 0, 0);
    }
  }

  // C/D layout: col = lane&15, row = (lane>>4)*4 + reg
#pragma unroll
  for (int nn = 0; nn < 4; ++nn) {
#pragma unroll
    for (int r = 0; r < 4; ++r) {
      int row = row0 + quad * 4 + r;
      int col = wave * 64 + nn * 16 + l15;
      if (row < M) C[(size_t)row * N + col] = (bf16)acc[nn][r];
    }
  }
}

// ---------------- aggregation: out[n] = act( sum_e w_e * T[src_e] + bias ) ----------------
// one wave per node; lane owns 4 features. All indices clamped.
__global__ __launch_bounds__(256) void agg_kernel(const bf16* __restrict__ T,
                                                  const int* __restrict__ perm_src,
                                                  const float* __restrict__ perm_w,
                                                  const int* __restrict__ offsets,
                                                  const float* __restrict__ bias,
                                                  bf16* __restrict__ Out, int N, int E,
                                                  int do_relu) {
  int node = blockIdx.x * 4 + (threadIdx.x >> 6);
  if (node >= N) return;
  int lane = threadIdx.x & 63;
  int f = lane * 4;
  int beg = offsets[node], end = offsets[node + 1];
  beg = beg < 0 ? 0 : (beg > E ? E : beg);
  end = end < beg ? beg : (end > E ? E : end);
  float a0 = 0.f, a1 = 0.f, a2 = 0.f, a3 = 0.f;
  for (int p = beg; p < end; ++p) {
    int s = perm_src[p];
    s = s < 0 ? 0 : (s >= N ? N - 1 : s);
    float w = perm_w[p];
    v4bf tv = *reinterpret_cast<const v4bf*>(T + (size_t)s * FDIM + f);
    a0 += w * (float)tv[0];
    a1 += w * (float)tv[1];
    a2 += w * (float)tv[2];
    a3 += w * (float)tv[3];
  }
  a0 += bias[f + 0];
  a1 += bias[f + 1];
  a2 += bias[f + 2];
  a3 += bias[f + 3];
  if (do_relu) {
    a0 = fmaxf(a0, 0.f); a1 = fmaxf(a1, 0.f);
    a2 = fmaxf(a2, 0.f); a3 = fmaxf(a3, 0.f);
  }
  v4bf o;
  o[0] = (bf16)a0; o[1] = (bf16)a1; o[2] = (bf16)a2; o[3] = (bf16)a3;
  *reinterpret_cast<v4bf*>(Out + (size_t)node * FDIM + f) = o;
}

// ---------------- query head: log_softmax(concat(h[q0],h[q1]) @ Wl + bl) ----------------
// one wave per query; lanes 0-31 -> q0 features, lanes 32-63 -> q1 features
// OUTPUT IS FP32 (reference output dtype).
__global__ __launch_bounds__(256) void query_kernel(const bf16* __restrict__ H,
                                                    const int* __restrict__ qe,
                                                    const float* __restrict__ Wl,
                                                    const float* __restrict__ bl,
                                                    float* __restrict__ out, int Q, int N) {
  int q = blockIdx.x * 4 + (threadIdx.x >> 6);
  if (q >= Q) return;
  int lane = threadIdx.x & 63;
  int half = lane >> 5;  // 0 -> q0 with Wl rows [0,256), 1 -> q1 with Wl rows [256,512)
  int sub = lane & 31;   // 8 features per lane
  int node = qe[2 * q + half];
  node = node < 0 ? 0 : (node >= N ? N - 1 : node);

  v8bf hv = *reinterpret_cast<const v8bf*>(H + (size_t)node * FDIM + sub * 8);
  const float* wl = Wl + (size_t)(half * 256 + sub * 8) * 2;  // [512,2] row-major, 16 floats

  float c0 = 0.f, c1 = 0.f;
#pragma unroll
  for (int j = 0; j < 8; ++j) {
    float hf = (float)hv[j];
    c0 += hf * wl[2 * j];
    c1 += hf * wl[2 * j + 1];
  }
#pragma unroll
  for (int d = 32; d > 0; d >>= 1) {
    c0 += __shfl_down(c0, d, 64);
    c1 += __shfl_down(c1, d, 64);
  }
  if (lane == 0) {
    float l0 = c0 + bl[0];
    float l1 = c1 + bl[1];
    float m = fmaxf(l0, l1);
    float lse = m + logf(expf(l0 - m) + expf(l1 - m));
    out[2 * q + 0] = l0 - lse;
    out[2 * q + 1] = l1 - lse;
  }
}

// ---------------- host launcher ----------------

extern "C" void kernel_launch(void* const* d_in, const int* in_sizes, int n_in,
                              void* d_out, int out_size, void* d_ws, size_t ws_size,
                              hipStream_t stream) {
  // Reference dtypes: float tensors fp32; edge_index/query_edges int32; OUTPUT fp32.
  const float* x  = (const float*)d_in[0];
  const int*   ei = (const int*)d_in[1];
  const int*   qe = (const int*)d_in[2];
  const float* ew = (const float*)d_in[3];
  const float* W1 = (const float*)d_in[4];
  const float* b1 = (const float*)d_in[5];
  const float* W2 = (const float*)d_in[6];
  const float* b2 = (const float*)d_in[7];
  const float* Wl = (const float*)d_in[8];
  const float* bl = (const float*)d_in[9];

  int N = in_sizes[0] / FDIM;  // 50000 nodes
  int E = in_sizes[1] / 2;     // 1,000,000 edges
  int Q = in_sizes[2] / 2;     // 100,000 queries
  const int* srcv = ei;
  const int* dstv = ei + E;

  size_t off = 0;
  auto alloc = [&](size_t bytes) -> void* {
    void* p = (char*)d_ws + off;
    off += (bytes + 255) & ~(size_t)255;
    return p;
  };
  bf16* bufT  = (bf16*)alloc((size_t)N * FDIM * 2);  // gemm output (reused layer 2)
  bf16* bufH1 = (bf16*)alloc((size_t)N * FDIM * 2);  // relu(conv1); reused as h2
  bf16* Wt1   = (bf16*)alloc((size_t)FDIM * FDIM * 2);
  bf16* Wt2   = (bf16*)alloc((size_t)FDIM * FDIM * 2);
  int* counts = (int*)alloc((size_t)N * 4);
  int* offs   = (int*)alloc((size_t)(N + 1) * 4);
  int* cursor = (int*)alloc((size_t)N * 4);
  int* psrc   = (int*)alloc((size_t)E * 4);
  float* pw   = (float*)alloc((size_t)E * 4);
  bf16* bufH2 = bufH1;  // h1 dead after gemm2; alias to save workspace

  if (off > ws_size) {
    flag_kernel<<<(out_size + 255) / 256, 256, 0, stream>>>((float*)d_out, out_size);
    return;
  }

  // CSR build (edge_index is identical every launch, but ws is re-poisoned)
  zero_kernel<<<(N + 255) / 256, 256, 0, stream>>>(counts, N);
  transpose_w<<<FDIM, FDIM, 0, stream>>>(W1, Wt1);
  transpose_w<<<FDIM, FDIM, 0, stream>>>(W2, Wt2);
  hist_kernel<<<2048, 256, 0, stream>>>(dstv, counts, E, N);
  scan_simple<<<1, 256, 0, stream>>>(counts, offs, cursor, N);
  scatter_kernel<<<2048, 256, 0, stream>>>(srcv, dstv, ew, cursor, psrc, pw, E, N);

  // layer 1: t = x@W1 ; h1 = relu(agg(t) + b1)
  gemm_kernel<float><<<(N + 15) / 16, 256, 0, stream>>>(x, Wt1, bufT, N);
  agg_kernel<<<(N + 3) / 4, 256, 0, stream>>>(bufT, psrc, pw, offs, b1, bufH1, N, E, 1);

  // layer 2: t = h1@W2 ; h2 = agg(t) + b2
  gemm_kernel<bf16><<<(N + 15) / 16, 256, 0, stream>>>(bufH1, Wt2, bufT, N);
  agg_kernel<<<(N + 3) / 4, 256, 0, stream>>>(bufT, psrc, pw, offs, b2, bufH2, N, E, 0);

  // head
  query_kernel<<<(Q + 3) / 4, 256, 0, stream>>>(bufH2, qe, Wl, bl, (float*)d_out, Q, N);
}

// Round 5
// 599.983 us; speedup vs baseline: 1.1838x; 1.1838x over previous
//
#include <hip/hip_runtime.h>
#include <hip/hip_bf16.h>
#include <math.h>

typedef __bf16 bf16;
typedef __bf16 v8bf __attribute__((ext_vector_type(8)));
typedef __bf16 v4bf __attribute__((ext_vector_type(4)));
typedef float  v4f  __attribute__((ext_vector_type(4)));

#define FDIM 256

// ---------------- small utility kernels ----------------

__global__ __launch_bounds__(256) void zero_kernel(int* __restrict__ p, int n) {
  int i = blockIdx.x * 256 + threadIdx.x;
  if (i < n) p[i] = 0;
}

// distinctive flag value if workspace is too small
__global__ __launch_bounds__(256) void flag_kernel(float* __restrict__ out, int n) {
  int i = blockIdx.x * 256 + threadIdx.x;
  if (i < n) out[i] = 1.0e9f;
}

// Wt[n*256 + k] = bf16(W[k*256 + n])  (B-fragment friendly: contiguous along k)
__global__ __launch_bounds__(256) void transpose_w(const float* __restrict__ W,
                                                   bf16* __restrict__ Wt) {
  int k = blockIdx.x;   // 0..255
  int n = threadIdx.x;  // 0..255
  Wt[n * FDIM + k] = (bf16)W[k * FDIM + n];
}

__global__ __launch_bounds__(256) void hist_kernel(const int* __restrict__ dst,
                                                   int* __restrict__ counts, int E, int N) {
  for (int e = blockIdx.x * 256 + threadIdx.x; e < E; e += gridDim.x * 256) {
    int d = dst[e];
    d = d < 0 ? 0 : (d >= N ? N - 1 : d);
    atomicAdd(&counts[d], 1);
  }
}

// ---------------- 3-phase parallel exclusive scan ----------------
// 1024 elements per block; thread t owns counts[b*1024 + 4t .. +4t+3] (int4, coalesced)

// phase A: per-block sums
__global__ __launch_bounds__(256) void scan_phase_a(const int* __restrict__ counts,
                                                    int* __restrict__ bsum, int n) {
  int t = threadIdx.x;
  int base = blockIdx.x * 1024 + t * 4;
  int4 v = {0, 0, 0, 0};
  if (base + 3 < n) v = *reinterpret_cast<const int4*>(counts + base);
  else {
    if (base + 0 < n) v.x = counts[base + 0];
    if (base + 1 < n) v.y = counts[base + 1];
    if (base + 2 < n) v.z = counts[base + 2];
  }
  int s = v.x + v.y + v.z + v.w;
#pragma unroll
  for (int d = 32; d > 0; d >>= 1) s += __shfl_down(s, d, 64);
  __shared__ int ws[4];
  if ((t & 63) == 0) ws[t >> 6] = s;
  __syncthreads();
  if (t == 0) bsum[blockIdx.x] = ws[0] + ws[1] + ws[2] + ws[3];
}

// phase B: single tiny block scans the ~49 block sums; writes offsets[n] = total
__global__ __launch_bounds__(64) void scan_phase_b(const int* __restrict__ bsum,
                                                   int* __restrict__ bpre,
                                                   int* __restrict__ offsets, int nb, int n) {
  if (threadIdx.x == 0) {
    int run = 0;
    for (int i = 0; i < nb; ++i) { bpre[i] = run; run += bsum[i]; }
    offsets[n] = run;
  }
}

// phase C: per-block exclusive scan + global offset; writes offsets and cursor
__global__ __launch_bounds__(256) void scan_phase_c(const int* __restrict__ counts,
                                                    const int* __restrict__ bpre,
                                                    int* __restrict__ offsets,
                                                    int* __restrict__ cursor, int n) {
  int t = threadIdx.x, lane = t & 63, wv = t >> 6;
  int base = blockIdx.x * 1024 + t * 4;
  int4 v = {0, 0, 0, 0};
  if (base + 3 < n) v = *reinterpret_cast<const int4*>(counts + base);
  else {
    if (base + 0 < n) v.x = counts[base + 0];
    if (base + 1 < n) v.y = counts[base + 1];
    if (base + 2 < n) v.z = counts[base + 2];
  }
  int s = v.x + v.y + v.z + v.w;
  int x = s;
#pragma unroll
  for (int d = 1; d < 64; d <<= 1) {
    int y = __shfl_up(x, d, 64);
    if (lane >= d) x += y;
  }
  __shared__ int ws[4];
  if (lane == 63) ws[wv] = x;
  __syncthreads();
  int woff = 0;
  if (wv >= 1) woff += ws[0];
  if (wv >= 2) woff += ws[1];
  if (wv >= 3) woff += ws[2];
  int excl = bpre[blockIdx.x] + woff + (x - s);
  int4 o;
  o.x = excl;
  o.y = o.x + v.x;
  o.z = o.y + v.y;
  o.w = o.z + v.z;
  if (base + 3 < n) {
    *reinterpret_cast<int4*>(offsets + base) = o;
    *reinterpret_cast<int4*>(cursor + base) = o;
  } else {
    if (base + 0 < n) { offsets[base + 0] = o.x; cursor[base + 0] = o.x; }
    if (base + 1 < n) { offsets[base + 1] = o.y; cursor[base + 1] = o.y; }
    if (base + 2 < n) { offsets[base + 2] = o.z; cursor[base + 2] = o.z; }
  }
}

__global__ __launch_bounds__(256) void scatter_kernel(const int* __restrict__ src,
                                                      const int* __restrict__ dst,
                                                      const float* __restrict__ ew,
                                                      int* __restrict__ cursor,
                                                      int* __restrict__ perm_src,
                                                      float* __restrict__ perm_w,
                                                      int E, int N) {
  for (int e = blockIdx.x * 256 + threadIdx.x; e < E; e += gridDim.x * 256) {
    int d = dst[e];
    d = d < 0 ? 0 : (d >= N ? N - 1 : d);
    int pos = atomicAdd(&cursor[d], 1);
    if (pos >= 0 && pos < E) {
      int sv = src[e];
      sv = sv < 0 ? 0 : (sv >= N ? N - 1 : sv);
      perm_src[pos] = sv;
      perm_w[pos] = ew[e];
    }
  }
}

// ---------------- A-fragment loaders (8 contiguous k-elements) ----------------
__device__ inline v8bf load8(const bf16* __restrict__ p) {
  return *reinterpret_cast<const v8bf*>(p);
}
__device__ inline v8bf load8(const float* __restrict__ p) {
  float4 a = *reinterpret_cast<const float4*>(p);
  float4 b = *reinterpret_cast<const float4*>(p + 4);
  v8bf r;
  r[0] = (bf16)a.x; r[1] = (bf16)a.y; r[2] = (bf16)a.z; r[3] = (bf16)a.w;
  r[4] = (bf16)b.x; r[5] = (bf16)b.y; r[6] = (bf16)b.z; r[7] = (bf16)b.w;
  return r;
}

// ---------------- GEMM: C[M,256] = A[M,256] @ W[256,256] ----------------
// A row-major (fp32 or bf16); Bt is W pre-transposed bf16: Bt[n*256+k] = W[k][n].
// Block = 256 threads = 4 waves; block tile = 16 rows x 256 cols;
// wave w covers cols [64w, 64w+64) via 4 accumulators of 16x16.
template <typename AT>
__global__ __launch_bounds__(256) void gemm_kernel(const AT* __restrict__ A,
                                                   const bf16* __restrict__ Bt,
                                                   bf16* __restrict__ C, int M) {
  const int K = FDIM, N = FDIM;
  int row0 = blockIdx.x * 16;
  int tid = threadIdx.x;
  int wave = tid >> 6;
  int lane = tid & 63;
  int l15 = lane & 15, quad = lane >> 4;

  int ar = row0 + l15;
  if (ar >= M) ar = M - 1;

  const AT* Arow = A + (size_t)ar * K + quad * 8;
  const bf16* Bbase = Bt + (size_t)(wave * 64 + l15) * K + quad * 8;

  v4f acc[4];
#pragma unroll
  for (int nn = 0; nn < 4; ++nn) acc[nn] = (v4f){0.f, 0.f, 0.f, 0.f};

#pragma unroll
  for (int kk = 0; kk < K; kk += 32) {
    v8bf a = load8(Arow + kk);
#pragma unroll
    for (int nn = 0; nn < 4; ++nn) {
      v8bf b = *reinterpret_cast<const v8bf*>(Bbase + (size_t)nn * 16 * K + kk);
      acc[nn] = __builtin_amdgcn_mfma_f32_16x16x32_bf16(a, b, acc[nn], 0, 0, 0);
    }
  }

  // C/D layout: col = lane&15, row = (lane>>4)*4 + reg
#pragma unroll
  for (int nn = 0; nn < 4; ++nn) {
#pragma unroll
    for (int r = 0; r < 4; ++r) {
      int row = row0 + quad * 4 + r;
      int col = wave * 64 + nn * 16 + l15;
      if (row < M) C[(size_t)row * N + col] = (bf16)acc[nn][r];
    }
  }
}

// ---------------- aggregation: out[n] = act( sum_e w_e * T[src_e] + bias ) ----------------
// one wave per node; lane owns 4 features. All indices clamped.
__global__ __launch_bounds__(256) void agg_kernel(const bf16* __restrict__ T,
                                                  const int* __restrict__ perm_src,
                                                  const float* __restrict__ perm_w,
                                                  const int* __restrict__ offsets,
                                                  const float* __restrict__ bias,
                                                  bf16* __restrict__ Out, int N, int E,
                                                  int do_relu) {
  int node = blockIdx.x * 4 + (threadIdx.x >> 6);
  if (node >= N) return;
  int lane = threadIdx.x & 63;
  int f = lane * 4;
  int beg = offsets[node], end = offsets[node + 1];
  beg = beg < 0 ? 0 : (beg > E ? E : beg);
  end = end < beg ? beg : (end > E ? E : end);
  float a0 = 0.f, a1 = 0.f, a2 = 0.f, a3 = 0.f;
  for (int p = beg; p < end; ++p) {
    int s = perm_src[p];
    s = s < 0 ? 0 : (s >= N ? N - 1 : s);
    float w = perm_w[p];
    v4bf tv = *reinterpret_cast<const v4bf*>(T + (size_t)s * FDIM + f);
    a0 += w * (float)tv[0];
    a1 += w * (float)tv[1];
    a2 += w * (float)tv[2];
    a3 += w * (float)tv[3];
  }
  a0 += bias[f + 0];
  a1 += bias[f + 1];
  a2 += bias[f + 2];
  a3 += bias[f + 3];
  if (do_relu) {
    a0 = fmaxf(a0, 0.f); a1 = fmaxf(a1, 0.f);
    a2 = fmaxf(a2, 0.f); a3 = fmaxf(a3, 0.f);
  }
  v4bf o;
  o[0] = (bf16)a0; o[1] = (bf16)a1; o[2] = (bf16)a2; o[3] = (bf16)a3;
  *reinterpret_cast<v4bf*>(Out + (size_t)node * FDIM + f) = o;
}

// ---------------- query head: log_softmax(concat(h[q0],h[q1]) @ Wl + bl) ----------------
// one wave per query; lanes 0-31 -> q0 features, lanes 32-63 -> q1 features
// OUTPUT IS FP32 (reference output dtype).
__global__ __launch_bounds__(256) void query_kernel(const bf16* __restrict__ H,
                                                    const int* __restrict__ qe,
                                                    const float* __restrict__ Wl,
                                                    const float* __restrict__ bl,
                                                    float* __restrict__ out, int Q, int N) {
  int q = blockIdx.x * 4 + (threadIdx.x >> 6);
  if (q >= Q) return;
  int lane = threadIdx.x & 63;
  int half = lane >> 5;  // 0 -> q0 with Wl rows [0,256), 1 -> q1 with Wl rows [256,512)
  int sub = lane & 31;   // 8 features per lane
  int node = qe[2 * q + half];
  node = node < 0 ? 0 : (node >= N ? N - 1 : node);

  v8bf hv = *reinterpret_cast<const v8bf*>(H + (size_t)node * FDIM + sub * 8);
  const float* wl = Wl + (size_t)(half * 256 + sub * 8) * 2;  // [512,2] row-major, 16 floats

  float c0 = 0.f, c1 = 0.f;
#pragma unroll
  for (int j = 0; j < 8; ++j) {
    float hf = (float)hv[j];
    c0 += hf * wl[2 * j];
    c1 += hf * wl[2 * j + 1];
  }
#pragma unroll
  for (int d = 32; d > 0; d >>= 1) {
    c0 += __shfl_down(c0, d, 64);
    c1 += __shfl_down(c1, d, 64);
  }
  if (lane == 0) {
    float l0 = c0 + bl[0];
    float l1 = c1 + bl[1];
    float m = fmaxf(l0, l1);
    float lse = m + logf(expf(l0 - m) + expf(l1 - m));
    out[2 * q + 0] = l0 - lse;
    out[2 * q + 1] = l1 - lse;
  }
}

// ---------------- host launcher ----------------

extern "C" void kernel_launch(void* const* d_in, const int* in_sizes, int n_in,
                              void* d_out, int out_size, void* d_ws, size_t ws_size,
                              hipStream_t stream) {
  // Reference dtypes: float tensors fp32; edge_index/query_edges int32; OUTPUT fp32.
  const float* x  = (const float*)d_in[0];
  const int*   ei = (const int*)d_in[1];
  const int*   qe = (const int*)d_in[2];
  const float* ew = (const float*)d_in[3];
  const float* W1 = (const float*)d_in[4];
  const float* b1 = (const float*)d_in[5];
  const float* W2 = (const float*)d_in[6];
  const float* b2 = (const float*)d_in[7];
  const float* Wl = (const float*)d_in[8];
  const float* bl = (const float*)d_in[9];

  int N = in_sizes[0] / FDIM;  // 50000 nodes
  int E = in_sizes[1] / 2;     // 1,000,000 edges
  int Q = in_sizes[2] / 2;     // 100,000 queries
  const int* srcv = ei;
  const int* dstv = ei + E;
  int NB = (N + 1023) / 1024;  // scan blocks

  size_t off = 0;
  auto alloc = [&](size_t bytes) -> void* {
    void* p = (char*)d_ws + off;
    off += (bytes + 255) & ~(size_t)255;
    return p;
  };
  bf16* bufT  = (bf16*)alloc((size_t)N * FDIM * 2);  // gemm output (reused layer 2)
  bf16* bufH1 = (bf16*)alloc((size_t)N * FDIM * 2);  // relu(conv1); reused as h2
  bf16* Wt1   = (bf16*)alloc((size_t)FDIM * FDIM * 2);
  bf16* Wt2   = (bf16*)alloc((size_t)FDIM * FDIM * 2);
  int* counts = (int*)alloc((size_t)N * 4);
  int* offs   = (int*)alloc((size_t)(N + 1) * 4);
  int* cursor = (int*)alloc((size_t)N * 4);
  int* psrc   = (int*)alloc((size_t)E * 4);
  float* pw   = (float*)alloc((size_t)E * 4);
  int* bsum   = (int*)alloc((size_t)NB * 4);
  int* bpre   = (int*)alloc((size_t)NB * 4);
  bf16* bufH2 = bufH1;  // h1 dead after gemm2; alias to save workspace

  if (off > ws_size) {
    flag_kernel<<<(out_size + 255) / 256, 256, 0, stream>>>((float*)d_out, out_size);
    return;
  }

  // CSR build (edge_index is identical every launch, but ws is re-poisoned)
  zero_kernel<<<(N + 255) / 256, 256, 0, stream>>>(counts, N);
  transpose_w<<<FDIM, FDIM, 0, stream>>>(W1, Wt1);
  transpose_w<<<FDIM, FDIM, 0, stream>>>(W2, Wt2);
  hist_kernel<<<2048, 256, 0, stream>>>(dstv, counts, E, N);
  scan_phase_a<<<NB, 256, 0, stream>>>(counts, bsum, N);
  scan_phase_b<<<1, 64, 0, stream>>>(bsum, bpre, offs, NB, N);
  scan_phase_c<<<NB, 256, 0, stream>>>(counts, bpre, offs, cursor, N);
  scatter_kernel<<<2048, 256, 0, stream>>>(srcv, dstv, ew, cursor, psrc, pw, E, N);

  // layer 1: t = x@W1 ; h1 = relu(agg(t) + b1)
  gemm_kernel<float><<<(N + 15) / 16, 256, 0, stream>>>(x, Wt1, bufT, N);
  agg_kernel<<<(N + 3) / 4, 256, 0, stream>>>(bufT, psrc, pw, offs, b1, bufH1, N, E, 1);

  // layer 2: t = h1@W2 ; h2 = agg(t) + b2
  gemm_kernel<bf16><<<(N + 15) / 16, 256, 0, stream>>>(bufH1, Wt2, bufT, N);
  agg_kernel<<<(N + 3) / 4, 256, 0, stream>>>(bufT, psrc, pw, offs, b2, bufH2, N, E, 0);

  // head
  query_kernel<<<(Q + 3) / 4, 256, 0, stream>>>(bufH2, qe, Wl, bl, (float*)d_out, Q, N);
}

// Round 6
// 522.182 us; speedup vs baseline: 1.3602x; 1.1490x over previous
//
#include <hip/hip_runtime.h>
#include <hip/hip_bf16.h>
#include <math.h>

typedef __bf16 bf16;
typedef __bf16 v8bf __attribute__((ext_vector_type(8)));
typedef __bf16 v4bf __attribute__((ext_vector_type(4)));
typedef float  v4f  __attribute__((ext_vector_type(4)));

#define FDIM 256

// ---------------- small utility kernels ----------------

__global__ __launch_bounds__(256) void zero_kernel(int* __restrict__ p, int n) {
  int i = blockIdx.x * 256 + threadIdx.x;
  if (i < n) p[i] = 0;
}

// distinctive flag value if workspace is too small
__global__ __launch_bounds__(256) void flag_kernel(float* __restrict__ out, int n) {
  int i = blockIdx.x * 256 + threadIdx.x;
  if (i < n) out[i] = 1.0e9f;
}

// Wt[n*256 + k] = bf16(W[k*256 + n])  (B-fragment friendly: contiguous along k)
__global__ __launch_bounds__(256) void transpose_w(const float* __restrict__ W,
                                                   bf16* __restrict__ Wt) {
  int k = blockIdx.x;   // 0..255
  int n = threadIdx.x;  // 0..255
  Wt[n * FDIM + k] = (bf16)W[k * FDIM + n];
}

__global__ __launch_bounds__(256) void hist_kernel(const int* __restrict__ dst,
                                                   int* __restrict__ counts, int E, int N) {
  for (int e = blockIdx.x * 256 + threadIdx.x; e < E; e += gridDim.x * 256) {
    int d = dst[e];
    d = d < 0 ? 0 : (d >= N ? N - 1 : d);
    atomicAdd(&counts[d], 1);
  }
}

// ---------------- 3-phase parallel exclusive scan ----------------
// 1024 elements per block; thread t owns counts[b*1024 + 4t .. +4t+3] (int4, coalesced)

// phase A: per-block sums
__global__ __launch_bounds__(256) void scan_phase_a(const int* __restrict__ counts,
                                                    int* __restrict__ bsum, int n) {
  int t = threadIdx.x;
  int base = blockIdx.x * 1024 + t * 4;
  int4 v = {0, 0, 0, 0};
  if (base + 3 < n) v = *reinterpret_cast<const int4*>(counts + base);
  else {
    if (base + 0 < n) v.x = counts[base + 0];
    if (base + 1 < n) v.y = counts[base + 1];
    if (base + 2 < n) v.z = counts[base + 2];
  }
  int s = v.x + v.y + v.z + v.w;
#pragma unroll
  for (int d = 32; d > 0; d >>= 1) s += __shfl_down(s, d, 64);
  __shared__ int ws[4];
  if ((t & 63) == 0) ws[t >> 6] = s;
  __syncthreads();
  if (t == 0) bsum[blockIdx.x] = ws[0] + ws[1] + ws[2] + ws[3];
}

// phase B: single tiny block scans the ~49 block sums; writes offsets[n] = total
__global__ __launch_bounds__(64) void scan_phase_b(const int* __restrict__ bsum,
                                                   int* __restrict__ bpre,
                                                   int* __restrict__ offsets, int nb, int n) {
  if (threadIdx.x == 0) {
    int run = 0;
    for (int i = 0; i < nb; ++i) { bpre[i] = run; run += bsum[i]; }
    offsets[n] = run;
  }
}

// phase C: per-block exclusive scan + global offset; writes offsets and cursor
__global__ __launch_bounds__(256) void scan_phase_c(const int* __restrict__ counts,
                                                    const int* __restrict__ bpre,
                                                    int* __restrict__ offsets,
                                                    int* __restrict__ cursor, int n) {
  int t = threadIdx.x, lane = t & 63, wv = t >> 6;
  int base = blockIdx.x * 1024 + t * 4;
  int4 v = {0, 0, 0, 0};
  if (base + 3 < n) v = *reinterpret_cast<const int4*>(counts + base);
  else {
    if (base + 0 < n) v.x = counts[base + 0];
    if (base + 1 < n) v.y = counts[base + 1];
    if (base + 2 < n) v.z = counts[base + 2];
  }
  int s = v.x + v.y + v.z + v.w;
  int x = s;
#pragma unroll
  for (int d = 1; d < 64; d <<= 1) {
    int y = __shfl_up(x, d, 64);
    if (lane >= d) x += y;
  }
  __shared__ int ws[4];
  if (lane == 63) ws[wv] = x;
  __syncthreads();
  int woff = 0;
  if (wv >= 1) woff += ws[0];
  if (wv >= 2) woff += ws[1];
  if (wv >= 3) woff += ws[2];
  int excl = bpre[blockIdx.x] + woff + (x - s);
  int4 o;
  o.x = excl;
  o.y = o.x + v.x;
  o.z = o.y + v.y;
  o.w = o.z + v.z;
  if (base + 3 < n) {
    *reinterpret_cast<int4*>(offsets + base) = o;
    *reinterpret_cast<int4*>(cursor + base) = o;
  } else {
    if (base + 0 < n) { offsets[base + 0] = o.x; cursor[base + 0] = o.x; }
    if (base + 1 < n) { offsets[base + 1] = o.y; cursor[base + 1] = o.y; }
    if (base + 2 < n) { offsets[base + 2] = o.z; cursor[base + 2] = o.z; }
  }
}

// scatter: build permuted (src, weight) pairs packed as int2 (one 8B load/edge in agg)
__global__ __launch_bounds__(256) void scatter_kernel(const int* __restrict__ src,
                                                      const int* __restrict__ dst,
                                                      const float* __restrict__ ew,
                                                      int* __restrict__ cursor,
                                                      int2* __restrict__ pmeta,
                                                      int E, int N) {
  for (int e = blockIdx.x * 256 + threadIdx.x; e < E; e += gridDim.x * 256) {
    int d = dst[e];
    d = d < 0 ? 0 : (d >= N ? N - 1 : d);
    int pos = atomicAdd(&cursor[d], 1);
    if (pos >= 0 && pos < E) {
      int sv = src[e];
      sv = sv < 0 ? 0 : (sv >= N ? N - 1 : sv);
      pmeta[pos] = make_int2(sv, __float_as_int(ew[e]));
    }
  }
}

// ---------------- A-fragment loaders (8 contiguous k-elements) ----------------
__device__ inline v8bf load8(const bf16* __restrict__ p) {
  return *reinterpret_cast<const v8bf*>(p);
}
__device__ inline v8bf load8(const float* __restrict__ p) {
  float4 a = *reinterpret_cast<const float4*>(p);
  float4 b = *reinterpret_cast<const float4*>(p + 4);
  v8bf r;
  r[0] = (bf16)a.x; r[1] = (bf16)a.y; r[2] = (bf16)a.z; r[3] = (bf16)a.w;
  r[4] = (bf16)b.x; r[5] = (bf16)b.y; r[6] = (bf16)b.z; r[7] = (bf16)b.w;
  return r;
}

// ---------------- GEMM: C[M,256] = A[M,256] @ W[256,256] ----------------
template <typename AT>
__global__ __launch_bounds__(256) void gemm_kernel(const AT* __restrict__ A,
                                                   const bf16* __restrict__ Bt,
                                                   bf16* __restrict__ C, int M) {
  const int K = FDIM, N = FDIM;
  int row0 = blockIdx.x * 16;
  int tid = threadIdx.x;
  int wave = tid >> 6;
  int lane = tid & 63;
  int l15 = lane & 15, quad = lane >> 4;

  int ar = row0 + l15;
  if (ar >= M) ar = M - 1;

  const AT* Arow = A + (size_t)ar * K + quad * 8;
  const bf16* Bbase = Bt + (size_t)(wave * 64 + l15) * K + quad * 8;

  v4f acc[4];
#pragma unroll
  for (int nn = 0; nn < 4; ++nn) acc[nn] = (v4f){0.f, 0.f, 0.f, 0.f};

#pragma unroll
  for (int kk = 0; kk < K; kk += 32) {
    v8bf a = load8(Arow + kk);
#pragma unroll
    for (int nn = 0; nn < 4; ++nn) {
      v8bf b = *reinterpret_cast<const v8bf*>(Bbase + (size_t)nn * 16 * K + kk);
      acc[nn] = __builtin_amdgcn_mfma_f32_16x16x32_bf16(a, b, acc[nn], 0, 0, 0);
    }
  }

  // C/D layout: col = lane&15, row = (lane>>4)*4 + reg
#pragma unroll
  for (int nn = 0; nn < 4; ++nn) {
#pragma unroll
    for (int r = 0; r < 4; ++r) {
      int row = row0 + quad * 4 + r;
      int col = wave * 64 + nn * 16 + l15;
      if (row < M) C[(size_t)row * N + col] = (bf16)acc[nn][r];
    }
  }
}

// ---------------- aggregation: out[n] = act( sum_e w_e * T[src_e] + bias ) ----------------
// one wave per node; lane owns 4 features. Edge loop unrolled x4 so 4 independent
// 512B gathers are in flight per wave (latency/MLP-bound fix, round 6).
__global__ __launch_bounds__(256) void agg_kernel(const bf16* __restrict__ T,
                                                  const int2* __restrict__ pmeta,
                                                  const int* __restrict__ offsets,
                                                  const float* __restrict__ bias,
                                                  bf16* __restrict__ Out, int N, int E,
                                                  int do_relu) {
  int node = blockIdx.x * 4 + (threadIdx.x >> 6);
  if (node >= N) return;
  int lane = threadIdx.x & 63;
  int f = lane * 4;
  int beg = offsets[node], end = offsets[node + 1];
  beg = beg < 0 ? 0 : (beg > E ? E : beg);
  end = end < beg ? beg : (end > E ? E : end);
  const int2* m = pmeta + beg;
  int cnt = end - beg;

  float a0 = 0.f, a1 = 0.f, a2 = 0.f, a3 = 0.f;
  int p = 0;
  for (; p + 4 <= cnt; p += 4) {
    int2 m0 = m[p + 0];
    int2 m1 = m[p + 1];
    int2 m2 = m[p + 2];
    int2 m3 = m[p + 3];
    int s0 = m0.x; s0 = s0 < 0 ? 0 : (s0 >= N ? N - 1 : s0);
    int s1 = m1.x; s1 = s1 < 0 ? 0 : (s1 >= N ? N - 1 : s1);
    int s2 = m2.x; s2 = s2 < 0 ? 0 : (s2 >= N ? N - 1 : s2);
    int s3 = m3.x; s3 = s3 < 0 ? 0 : (s3 >= N ? N - 1 : s3);
    v4bf t0 = *reinterpret_cast<const v4bf*>(T + (size_t)s0 * FDIM + f);
    v4bf t1 = *reinterpret_cast<const v4bf*>(T + (size_t)s1 * FDIM + f);
    v4bf t2 = *reinterpret_cast<const v4bf*>(T + (size_t)s2 * FDIM + f);
    v4bf t3 = *reinterpret_cast<const v4bf*>(T + (size_t)s3 * FDIM + f);
    float w0 = __int_as_float(m0.y);
    float w1 = __int_as_float(m1.y);
    float w2 = __int_as_float(m2.y);
    float w3 = __int_as_float(m3.y);
    a0 += w0 * (float)t0[0] + w1 * (float)t1[0] + w2 * (float)t2[0] + w3 * (float)t3[0];
    a1 += w0 * (float)t0[1] + w1 * (float)t1[1] + w2 * (float)t2[1] + w3 * (float)t3[1];
    a2 += w0 * (float)t0[2] + w1 * (float)t1[2] + w2 * (float)t2[2] + w3 * (float)t3[2];
    a3 += w0 * (float)t0[3] + w1 * (float)t1[3] + w2 * (float)t2[3] + w3 * (float)t3[3];
  }
  for (; p < cnt; ++p) {
    int2 mm = m[p];
    int s = mm.x; s = s < 0 ? 0 : (s >= N ? N - 1 : s);
    float w = __int_as_float(mm.y);
    v4bf tv = *reinterpret_cast<const v4bf*>(T + (size_t)s * FDIM + f);
    a0 += w * (float)tv[0];
    a1 += w * (float)tv[1];
    a2 += w * (float)tv[2];
    a3 += w * (float)tv[3];
  }
  a0 += bias[f + 0];
  a1 += bias[f + 1];
  a2 += bias[f + 2];
  a3 += bias[f + 3];
  if (do_relu) {
    a0 = fmaxf(a0, 0.f); a1 = fmaxf(a1, 0.f);
    a2 = fmaxf(a2, 0.f); a3 = fmaxf(a3, 0.f);
  }
  v4bf o;
  o[0] = (bf16)a0; o[1] = (bf16)a1; o[2] = (bf16)a2; o[3] = (bf16)a3;
  *reinterpret_cast<v4bf*>(Out + (size_t)node * FDIM + f) = o;
}

// ---------------- query head: log_softmax(concat(h[q0],h[q1]) @ Wl + bl) ----------------
__global__ __launch_bounds__(256) void query_kernel(const bf16* __restrict__ H,
                                                    const int* __restrict__ qe,
                                                    const float* __restrict__ Wl,
                                                    const float* __restrict__ bl,
                                                    float* __restrict__ out, int Q, int N) {
  int q = blockIdx.x * 4 + (threadIdx.x >> 6);
  if (q >= Q) return;
  int lane = threadIdx.x & 63;
  int half = lane >> 5;  // 0 -> q0 with Wl rows [0,256), 1 -> q1 with Wl rows [256,512)
  int sub = lane & 31;   // 8 features per lane
  int node = qe[2 * q + half];
  node = node < 0 ? 0 : (node >= N ? N - 1 : node);

  v8bf hv = *reinterpret_cast<const v8bf*>(H + (size_t)node * FDIM + sub * 8);
  const float* wl = Wl + (size_t)(half * 256 + sub * 8) * 2;  // [512,2] row-major, 16 floats

  float c0 = 0.f, c1 = 0.f;
#pragma unroll
  for (int j = 0; j < 8; ++j) {
    float hf = (float)hv[j];
    c0 += hf * wl[2 * j];
    c1 += hf * wl[2 * j + 1];
  }
#pragma unroll
  for (int d = 32; d > 0; d >>= 1) {
    c0 += __shfl_down(c0, d, 64);
    c1 += __shfl_down(c1, d, 64);
  }
  if (lane == 0) {
    float l0 = c0 + bl[0];
    float l1 = c1 + bl[1];
    float m = fmaxf(l0, l1);
    float lse = m + logf(expf(l0 - m) + expf(l1 - m));
    out[2 * q + 0] = l0 - lse;
    out[2 * q + 1] = l1 - lse;
  }
}

// ---------------- host launcher ----------------

extern "C" void kernel_launch(void* const* d_in, const int* in_sizes, int n_in,
                              void* d_out, int out_size, void* d_ws, size_t ws_size,
                              hipStream_t stream) {
  // Reference dtypes: float tensors fp32; edge_index/query_edges int32; OUTPUT fp32.
  const float* x  = (const float*)d_in[0];
  const int*   ei = (const int*)d_in[1];
  const int*   qe = (const int*)d_in[2];
  const float* ew = (const float*)d_in[3];
  const float* W1 = (const float*)d_in[4];
  const float* b1 = (const float*)d_in[5];
  const float* W2 = (const float*)d_in[6];
  const float* b2 = (const float*)d_in[7];
  const float* Wl = (const float*)d_in[8];
  const float* bl = (const float*)d_in[9];

  int N = in_sizes[0] / FDIM;  // 50000 nodes
  int E = in_sizes[1] / 2;     // 1,000,000 edges
  int Q = in_sizes[2] / 2;     // 100,000 queries
  const int* srcv = ei;
  const int* dstv = ei + E;
  int NB = (N + 1023) / 1024;  // scan blocks

  size_t off = 0;
  auto alloc = [&](size_t bytes) -> void* {
    void* p = (char*)d_ws + off;
    off += (bytes + 255) & ~(size_t)255;
    return p;
  };
  bf16* bufT  = (bf16*)alloc((size_t)N * FDIM * 2);  // gemm output (reused layer 2)
  bf16* bufH1 = (bf16*)alloc((size_t)N * FDIM * 2);  // relu(conv1); reused as h2
  bf16* Wt1   = (bf16*)alloc((size_t)FDIM * FDIM * 2);
  bf16* Wt2   = (bf16*)alloc((size_t)FDIM * FDIM * 2);
  int* counts = (int*)alloc((size_t)N * 4);
  int* offs   = (int*)alloc((size_t)(N + 1) * 4);
  int* cursor = (int*)alloc((size_t)N * 4);
  int2* pmeta = (int2*)alloc((size_t)E * 8);
  int* bsum   = (int*)alloc((size_t)NB * 4);
  int* bpre   = (int*)alloc((size_t)NB * 4);
  bf16* bufH2 = bufH1;  // h1 dead after gemm2; alias to save workspace

  if (off > ws_size) {
    flag_kernel<<<(out_size + 255) / 256, 256, 0, stream>>>((float*)d_out, out_size);
    return;
  }

  // CSR build (edge_index is identical every launch, but ws is re-poisoned)
  zero_kernel<<<(N + 255) / 256, 256, 0, stream>>>(counts, N);
  transpose_w<<<FDIM, FDIM, 0, stream>>>(W1, Wt1);
  transpose_w<<<FDIM, FDIM, 0, stream>>>(W2, Wt2);
  hist_kernel<<<2048, 256, 0, stream>>>(dstv, counts, E, N);
  scan_phase_a<<<NB, 256, 0, stream>>>(counts, bsum, N);
  scan_phase_b<<<1, 64, 0, stream>>>(bsum, bpre, offs, NB, N);
  scan_phase_c<<<NB, 256, 0, stream>>>(counts, bpre, offs, cursor, N);
  scatter_kernel<<<2048, 256, 0, stream>>>(srcv, dstv, ew, cursor, pmeta, E, N);

  // layer 1: t = x@W1 ; h1 = relu(agg(t) + b1)
  gemm_kernel<float><<<(N + 15) / 16, 256, 0, stream>>>(x, Wt1, bufT, N);
  agg_kernel<<<(N + 3) / 4, 256, 0, stream>>>(bufT, pmeta, offs, b1, bufH1, N, E, 1);

  // layer 2: t = h1@W2 ; h2 = agg(t) + b2
  gemm_kernel<bf16><<<(N + 15) / 16, 256, 0, stream>>>(bufH1, Wt2, bufT, N);
  agg_kernel<<<(N + 3) / 4, 256, 0, stream>>>(bufT, pmeta, offs, b2, bufH2, N, E, 0);

  // head
  query_kernel<<<(Q + 3) / 4, 256, 0, stream>>>(bufH2, qe, Wl, bl, (float*)d_out, Q, N);
}

// Round 7
// 451.542 us; speedup vs baseline: 1.5729x; 1.1564x over previous
//
#include <hip/hip_runtime.h>
#include <hip/hip_bf16.h>
#include <math.h>

typedef __bf16 bf16;
typedef __bf16 v8bf __attribute__((ext_vector_type(8)));
typedef __bf16 v4bf __attribute__((ext_vector_type(4)));
typedef float  v4f  __attribute__((ext_vector_type(4)));

#define FDIM 256

// ---------------- small utility kernels ----------------

__global__ __launch_bounds__(256) void zero_kernel(int* __restrict__ p, int n) {
  int i = blockIdx.x * 256 + threadIdx.x;
  if (i < n) p[i] = 0;
}

// distinctive flag value if workspace is too small
__global__ __launch_bounds__(256) void flag_kernel(float* __restrict__ out, int n) {
  int i = blockIdx.x * 256 + threadIdx.x;
  if (i < n) out[i] = 1.0e9f;
}

// Wt[n*256 + k] = bf16(W[k*256 + n])  (B-fragment friendly: contiguous along k)
__global__ __launch_bounds__(256) void transpose_w(const float* __restrict__ W,
                                                   bf16* __restrict__ Wt) {
  int k = blockIdx.x;   // 0..255
  int n = threadIdx.x;  // 0..255
  Wt[n * FDIM + k] = (bf16)W[k * FDIM + n];
}

__global__ __launch_bounds__(256) void hist_kernel(const int* __restrict__ dst,
                                                   int* __restrict__ counts, int E, int N) {
  for (int e = blockIdx.x * 256 + threadIdx.x; e < E; e += gridDim.x * 256) {
    int d = dst[e];
    d = d < 0 ? 0 : (d >= N ? N - 1 : d);
    atomicAdd(&counts[d], 1);
  }
}

// ---------------- 3-phase parallel exclusive scan ----------------
// 1024 elements per block; thread t owns counts[b*1024 + 4t .. +4t+3] (int4, coalesced)

// phase A: per-block sums
__global__ __launch_bounds__(256) void scan_phase_a(const int* __restrict__ counts,
                                                    int* __restrict__ bsum, int n) {
  int t = threadIdx.x;
  int base = blockIdx.x * 1024 + t * 4;
  int4 v = {0, 0, 0, 0};
  if (base + 3 < n) v = *reinterpret_cast<const int4*>(counts + base);
  else {
    if (base + 0 < n) v.x = counts[base + 0];
    if (base + 1 < n) v.y = counts[base + 1];
    if (base + 2 < n) v.z = counts[base + 2];
  }
  int s = v.x + v.y + v.z + v.w;
#pragma unroll
  for (int d = 32; d > 0; d >>= 1) s += __shfl_down(s, d, 64);
  __shared__ int ws[4];
  if ((t & 63) == 0) ws[t >> 6] = s;
  __syncthreads();
  if (t == 0) bsum[blockIdx.x] = ws[0] + ws[1] + ws[2] + ws[3];
}

// phase B: single tiny block scans the ~49 block sums; writes offsets[n] = total
__global__ __launch_bounds__(64) void scan_phase_b(const int* __restrict__ bsum,
                                                   int* __restrict__ bpre,
                                                   int* __restrict__ offsets, int nb, int n) {
  if (threadIdx.x == 0) {
    int run = 0;
    for (int i = 0; i < nb; ++i) { bpre[i] = run; run += bsum[i]; }
    offsets[n] = run;
  }
}

// phase C: per-block exclusive scan + global offset; writes offsets and cursor
__global__ __launch_bounds__(256) void scan_phase_c(const int* __restrict__ counts,
                                                    const int* __restrict__ bpre,
                                                    int* __restrict__ offsets,
                                                    int* __restrict__ cursor, int n) {
  int t = threadIdx.x, lane = t & 63, wv = t >> 6;
  int base = blockIdx.x * 1024 + t * 4;
  int4 v = {0, 0, 0, 0};
  if (base + 3 < n) v = *reinterpret_cast<const int4*>(counts + base);
  else {
    if (base + 0 < n) v.x = counts[base + 0];
    if (base + 1 < n) v.y = counts[base + 1];
    if (base + 2 < n) v.z = counts[base + 2];
  }
  int s = v.x + v.y + v.z + v.w;
  int x = s;
#pragma unroll
  for (int d = 1; d < 64; d <<= 1) {
    int y = __shfl_up(x, d, 64);
    if (lane >= d) x += y;
  }
  __shared__ int ws[4];
  if (lane == 63) ws[wv] = x;
  __syncthreads();
  int woff = 0;
  if (wv >= 1) woff += ws[0];
  if (wv >= 2) woff += ws[1];
  if (wv >= 3) woff += ws[2];
  int excl = bpre[blockIdx.x] + woff + (x - s);
  int4 o;
  o.x = excl;
  o.y = o.x + v.x;
  o.z = o.y + v.y;
  o.w = o.z + v.z;
  if (base + 3 < n) {
    *reinterpret_cast<int4*>(offsets + base) = o;
    *reinterpret_cast<int4*>(cursor + base) = o;
  } else {
    if (base + 0 < n) { offsets[base + 0] = o.x; cursor[base + 0] = o.x; }
    if (base + 1 < n) { offsets[base + 1] = o.y; cursor[base + 1] = o.y; }
    if (base + 2 < n) { offsets[base + 2] = o.z; cursor[base + 2] = o.z; }
  }
}

// scatter: build permuted (src, weight) pairs packed as int2 (one 8B load/edge in agg)
__global__ __launch_bounds__(256) void scatter_kernel(const int* __restrict__ src,
                                                      const int* __restrict__ dst,
                                                      const float* __restrict__ ew,
                                                      int* __restrict__ cursor,
                                                      int2* __restrict__ pmeta,
                                                      int E, int N) {
  for (int e = blockIdx.x * 256 + threadIdx.x; e < E; e += gridDim.x * 256) {
    int d = dst[e];
    d = d < 0 ? 0 : (d >= N ? N - 1 : d);
    int pos = atomicAdd(&cursor[d], 1);
    if (pos >= 0 && pos < E) {
      int sv = src[e];
      sv = sv < 0 ? 0 : (sv >= N ? N - 1 : sv);
      pmeta[pos] = make_int2(sv, __float_as_int(ew[e]));
    }
  }
}

// ---------------- A-fragment loaders (8 contiguous k-elements) ----------------
__device__ inline v8bf load8(const bf16* __restrict__ p) {
  return *reinterpret_cast<const v8bf*>(p);
}
__device__ inline v8bf load8(const float* __restrict__ p) {
  float4 a = *reinterpret_cast<const float4*>(p);
  float4 b = *reinterpret_cast<const float4*>(p + 4);
  v8bf r;
  r[0] = (bf16)a.x; r[1] = (bf16)a.y; r[2] = (bf16)a.z; r[3] = (bf16)a.w;
  r[4] = (bf16)b.x; r[5] = (bf16)b.y; r[6] = (bf16)b.z; r[7] = (bf16)b.w;
  return r;
}

// ---------------- GEMM: C[M,256] = A[M,256] @ W[256,256] ----------------
// v2 (round 7): B held entirely in registers per wave (4 col-tiles x 8 k-steps
// = 128 VGPRs of bf16 frags), loaded ONCE per block; block then strides over
// 16-row tiles of A. Kills the 400 MB/dispatch L1/L2 B re-read that made v1
// transaction-bound (MfmaUtil 3%, VALUBusy 5%, HBM 8%).
// __launch_bounds__(256,2): 2 blocks/CU -> VGPR cap 256 (est ~190, no spill).
template <typename AT>
__global__ __launch_bounds__(256, 2) void gemm_kernel(const AT* __restrict__ A,
                                                      const bf16* __restrict__ Bt,
                                                      bf16* __restrict__ C, int M) {
  const int K = FDIM, N = FDIM;
  int tid = threadIdx.x;
  int wave = tid >> 6;
  int lane = tid & 63;
  int l15 = lane & 15, quad = lane >> 4;

  // B fragments for this wave's 64 cols, entire K. bfr[nn][kk]:
  // lane holds Bt[(wave*64+nn*16+l15)*256 + kk*32 + quad*8 .. +8]
  v8bf bfr[4][8];
#pragma unroll
  for (int nn = 0; nn < 4; ++nn) {
    const bf16* bp = Bt + (size_t)(wave * 64 + nn * 16 + l15) * K + quad * 8;
#pragma unroll
    for (int kk = 0; kk < 8; ++kk)
      bfr[nn][kk] = *reinterpret_cast<const v8bf*>(bp + kk * 32);
  }

  int ntiles = (M + 15) >> 4;
  for (int tile = blockIdx.x; tile < ntiles; tile += gridDim.x) {
    int row0 = tile * 16;
    int ar = row0 + l15;
    if (ar >= M) ar = M - 1;
    const AT* Ap = A + (size_t)ar * K + quad * 8;

    v8bf afr[8];
#pragma unroll
    for (int kk = 0; kk < 8; ++kk) afr[kk] = load8(Ap + kk * 32);

    v4f acc[4];
#pragma unroll
    for (int nn = 0; nn < 4; ++nn) acc[nn] = (v4f){0.f, 0.f, 0.f, 0.f};

#pragma unroll
    for (int kk = 0; kk < 8; ++kk)
#pragma unroll
      for (int nn = 0; nn < 4; ++nn)
        acc[nn] = __builtin_amdgcn_mfma_f32_16x16x32_bf16(afr[kk], bfr[nn][kk], acc[nn], 0, 0, 0);

    // C/D layout: col = lane&15, row = (lane>>4)*4 + reg
#pragma unroll
    for (int nn = 0; nn < 4; ++nn)
#pragma unroll
      for (int r = 0; r < 4; ++r) {
        int row = row0 + quad * 4 + r;
        int col = wave * 64 + nn * 16 + l15;
        if (row < M) C[(size_t)row * N + col] = (bf16)acc[nn][r];
      }
  }
}

// ---------------- aggregation: out[n] = act( sum_e w_e * T[src_e] + bias ) ----------------
// one wave per node; lane owns 4 features. Edge loop unrolled x4 so 4 independent
// 512B gathers are in flight per wave.
__global__ __launch_bounds__(256) void agg_kernel(const bf16* __restrict__ T,
                                                  const int2* __restrict__ pmeta,
                                                  const int* __restrict__ offsets,
                                                  const float* __restrict__ bias,
                                                  bf16* __restrict__ Out, int N, int E,
                                                  int do_relu) {
  int node = blockIdx.x * 4 + (threadIdx.x >> 6);
  if (node >= N) return;
  int lane = threadIdx.x & 63;
  int f = lane * 4;
  int beg = offsets[node], end = offsets[node + 1];
  beg = beg < 0 ? 0 : (beg > E ? E : beg);
  end = end < beg ? beg : (end > E ? E : end);
  const int2* m = pmeta + beg;
  int cnt = end - beg;

  float a0 = 0.f, a1 = 0.f, a2 = 0.f, a3 = 0.f;
  int p = 0;
  for (; p + 4 <= cnt; p += 4) {
    int2 m0 = m[p + 0];
    int2 m1 = m[p + 1];
    int2 m2 = m[p + 2];
    int2 m3 = m[p + 3];
    int s0 = m0.x; s0 = s0 < 0 ? 0 : (s0 >= N ? N - 1 : s0);
    int s1 = m1.x; s1 = s1 < 0 ? 0 : (s1 >= N ? N - 1 : s1);
    int s2 = m2.x; s2 = s2 < 0 ? 0 : (s2 >= N ? N - 1 : s2);
    int s3 = m3.x; s3 = s3 < 0 ? 0 : (s3 >= N ? N - 1 : s3);
    v4bf t0 = *reinterpret_cast<const v4bf*>(T + (size_t)s0 * FDIM + f);
    v4bf t1 = *reinterpret_cast<const v4bf*>(T + (size_t)s1 * FDIM + f);
    v4bf t2 = *reinterpret_cast<const v4bf*>(T + (size_t)s2 * FDIM + f);
    v4bf t3 = *reinterpret_cast<const v4bf*>(T + (size_t)s3 * FDIM + f);
    float w0 = __int_as_float(m0.y);
    float w1 = __int_as_float(m1.y);
    float w2 = __int_as_float(m2.y);
    float w3 = __int_as_float(m3.y);
    a0 += w0 * (float)t0[0] + w1 * (float)t1[0] + w2 * (float)t2[0] + w3 * (float)t3[0];
    a1 += w0 * (float)t0[1] + w1 * (float)t1[1] + w2 * (float)t2[1] + w3 * (float)t3[1];
    a2 += w0 * (float)t0[2] + w1 * (float)t1[2] + w2 * (float)t2[2] + w3 * (float)t3[2];
    a3 += w0 * (float)t0[3] + w1 * (float)t1[3] + w2 * (float)t2[3] + w3 * (float)t3[3];
  }
  for (; p < cnt; ++p) {
    int2 mm = m[p];
    int s = mm.x; s = s < 0 ? 0 : (s >= N ? N - 1 : s);
    float w = __int_as_float(mm.y);
    v4bf tv = *reinterpret_cast<const v4bf*>(T + (size_t)s * FDIM + f);
    a0 += w * (float)tv[0];
    a1 += w * (float)tv[1];
    a2 += w * (float)tv[2];
    a3 += w * (float)tv[3];
  }
  a0 += bias[f + 0];
  a1 += bias[f + 1];
  a2 += bias[f + 2];
  a3 += bias[f + 3];
  if (do_relu) {
    a0 = fmaxf(a0, 0.f); a1 = fmaxf(a1, 0.f);
    a2 = fmaxf(a2, 0.f); a3 = fmaxf(a3, 0.f);
  }
  v4bf o;
  o[0] = (bf16)a0; o[1] = (bf16)a1; o[2] = (bf16)a2; o[3] = (bf16)a3;
  *reinterpret_cast<v4bf*>(Out + (size_t)node * FDIM + f) = o;
}

// ---------------- query head: log_softmax(concat(h[q0],h[q1]) @ Wl + bl) ----------------
__global__ __launch_bounds__(256) void query_kernel(const bf16* __restrict__ H,
                                                    const int* __restrict__ qe,
                                                    const float* __restrict__ Wl,
                                                    const float* __restrict__ bl,
                                                    float* __restrict__ out, int Q, int N) {
  int q = blockIdx.x * 4 + (threadIdx.x >> 6);
  if (q >= Q) return;
  int lane = threadIdx.x & 63;
  int half = lane >> 5;  // 0 -> q0 with Wl rows [0,256), 1 -> q1 with Wl rows [256,512)
  int sub = lane & 31;   // 8 features per lane
  int node = qe[2 * q + half];
  node = node < 0 ? 0 : (node >= N ? N - 1 : node);

  v8bf hv = *reinterpret_cast<const v8bf*>(H + (size_t)node * FDIM + sub * 8);
  const float* wl = Wl + (size_t)(half * 256 + sub * 8) * 2;  // [512,2] row-major, 16 floats

  float c0 = 0.f, c1 = 0.f;
#pragma unroll
  for (int j = 0; j < 8; ++j) {
    float hf = (float)hv[j];
    c0 += hf * wl[2 * j];
    c1 += hf * wl[2 * j + 1];
  }
#pragma unroll
  for (int d = 32; d > 0; d >>= 1) {
    c0 += __shfl_down(c0, d, 64);
    c1 += __shfl_down(c1, d, 64);
  }
  if (lane == 0) {
    float l0 = c0 + bl[0];
    float l1 = c1 + bl[1];
    float m = fmaxf(l0, l1);
    float lse = m + logf(expf(l0 - m) + expf(l1 - m));
    out[2 * q + 0] = l0 - lse;
    out[2 * q + 1] = l1 - lse;
  }
}

// ---------------- host launcher ----------------

extern "C" void kernel_launch(void* const* d_in, const int* in_sizes, int n_in,
                              void* d_out, int out_size, void* d_ws, size_t ws_size,
                              hipStream_t stream) {
  // Reference dtypes: float tensors fp32; edge_index/query_edges int32; OUTPUT fp32.
  const float* x  = (const float*)d_in[0];
  const int*   ei = (const int*)d_in[1];
  const int*   qe = (const int*)d_in[2];
  const float* ew = (const float*)d_in[3];
  const float* W1 = (const float*)d_in[4];
  const float* b1 = (const float*)d_in[5];
  const float* W2 = (const float*)d_in[6];
  const float* b2 = (const float*)d_in[7];
  const float* Wl = (const float*)d_in[8];
  const float* bl = (const float*)d_in[9];

  int N = in_sizes[0] / FDIM;  // 50000 nodes
  int E = in_sizes[1] / 2;     // 1,000,000 edges
  int Q = in_sizes[2] / 2;     // 100,000 queries
  const int* srcv = ei;
  const int* dstv = ei + E;
  int NB = (N + 1023) / 1024;  // scan blocks
  int ntiles = (N + 15) / 16;
  int gemm_grid = ntiles < 512 ? ntiles : 512;

  size_t off = 0;
  auto alloc = [&](size_t bytes) -> void* {
    void* p = (char*)d_ws + off;
    off += (bytes + 255) & ~(size_t)255;
    return p;
  };
  bf16* bufT  = (bf16*)alloc((size_t)N * FDIM * 2);  // gemm output (reused layer 2)
  bf16* bufH1 = (bf16*)alloc((size_t)N * FDIM * 2);  // relu(conv1); reused as h2
  bf16* Wt1   = (bf16*)alloc((size_t)FDIM * FDIM * 2);
  bf16* Wt2   = (bf16*)alloc((size_t)FDIM * FDIM * 2);
  int* counts = (int*)alloc((size_t)N * 4);
  int* offs   = (int*)alloc((size_t)(N + 1) * 4);
  int* cursor = (int*)alloc((size_t)N * 4);
  int2* pmeta = (int2*)alloc((size_t)E * 8);
  int* bsum   = (int*)alloc((size_t)NB * 4);
  int* bpre   = (int*)alloc((size_t)NB * 4);
  bf16* bufH2 = bufH1;  // h1 dead after gemm2; alias to save workspace

  if (off > ws_size) {
    flag_kernel<<<(out_size + 255) / 256, 256, 0, stream>>>((float*)d_out, out_size);
    return;
  }

  // CSR build (edge_index is identical every launch, but ws is re-poisoned)
  zero_kernel<<<(N + 255) / 256, 256, 0, stream>>>(counts, N);
  transpose_w<<<FDIM, FDIM, 0, stream>>>(W1, Wt1);
  transpose_w<<<FDIM, FDIM, 0, stream>>>(W2, Wt2);
  hist_kernel<<<2048, 256, 0, stream>>>(dstv, counts, E, N);
  scan_phase_a<<<NB, 256, 0, stream>>>(counts, bsum, N);
  scan_phase_b<<<1, 64, 0, stream>>>(bsum, bpre, offs, NB, N);
  scan_phase_c<<<NB, 256, 0, stream>>>(counts, bpre, offs, cursor, N);
  scatter_kernel<<<2048, 256, 0, stream>>>(srcv, dstv, ew, cursor, pmeta, E, N);

  // layer 1: t = x@W1 ; h1 = relu(agg(t) + b1)
  gemm_kernel<float><<<gemm_grid, 256, 0, stream>>>(x, Wt1, bufT, N);
  agg_kernel<<<(N + 3) / 4, 256, 0, stream>>>(bufT, pmeta, offs, b1, bufH1, N, E, 1);

  // layer 2: t = h1@W2 ; h2 = agg(t) + b2
  gemm_kernel<bf16><<<gemm_grid, 256, 0, stream>>>(bufH1, Wt2, bufT, N);
  agg_kernel<<<(N + 3) / 4, 256, 0, stream>>>(bufT, pmeta, offs, b2, bufH2, N, E, 0);

  // head
  query_kernel<<<(Q + 3) / 4, 256, 0, stream>>>(bufH2, qe, Wl, bl, (float*)d_out, Q, N);
}